// Round 12
// baseline (5439.621 us; speedup 1.0000x reference)
//
#include <hip/hip_runtime.h>

// ---------------- problem constants ----------------
#define T_SEQ 512
#define P_PRED 32
#define TP 544            // T_SEQ + P_PRED
#define BATCH 256
#define H 512
#define G4H 2048
// ---------------- kernel config --------------------
// ROUND-12 = ROUND-11 (best, 4129us) + two independent levers:
//  (1) SINGLE-ACTIVATION-PER-LANE: lane ln holds gate ln>>2's pre-act;
//      it applies its OWN gate's activation (unified a = ac0 + ac1*
//      rcp(1+exp(asc*z))), then the ACTIVATED values are shuffled.
//      Consumed lanes (ln<4) see bit-identical math to r11. Cuts 4 exp+
//      4 rcp down to 1+1 per value (~200-250cy/phase).
//  (2) FLAG PREFETCH: sample the group's flag line early (B's sample
//      issues after waitA -> hides under bodyA; next-round A's sample
//      issues after waitB -> hides under bodyB). Wait checks the sample
//      first; on miss falls back to the normal poll. Monotone flags make
//      early sampling safe. Main loop only; tail keeps plain xbar.
// All r11 invariants kept: 16 groups of 16 rows, group g on XCD g&7;
// 256 WGs = 8 XCDs x 32 slots; WG serves groups xcd, xcd+8 per round
// (age-1 A/B pipelining); weights in VGPRs (192/lane, 1 wave/SIMD
// mandatory - r8); flags agent-scope LIC atomics ONLY (r6+r10 proved SC0
// flags unsound); data SC0 at XCD L2 (r4); rcp activations (r9);
// conflict-free staging gran (r9); split MFMA chains (r11).
// Tripwires: absmax fail -> revert to r11; FETCH>=1GB -> r1 anomaly.
#define GRID 256
#define BLOCK 256
#define RPG 16              // rows per group
#define HBUF (BATCH*H)      // elements per h double-buffer slot
#define HBYTES (HBUF*2)
#define SCX 1               // CPol: SC0 -> bypass L1, coherent at XCD L2

typedef _Float16 half8 __attribute__((ext_vector_type(8)));
typedef float floatx4 __attribute__((ext_vector_type(4)));
typedef __amdgpu_buffer_rsrc_t rsrc_t;

#define MFMA(a,b,c) __builtin_amdgcn_mfma_f32_16x16x32_f16((a),(b),(c),0,0,0)

// ---------------- device-global state --------------
__device__ __attribute__((aligned(128))) _Float16 g_h1[2*HBUF];
__device__ __attribute__((aligned(128))) _Float16 g_h2[2*HBUF];
// o partials: [j = g*128 + slot*4 + w][t][32 slots (16 rows used)]
__device__ __attribute__((aligned(128))) float g_opart[(size_t)2048*TP*32];
__device__ __attribute__((aligned(128))) float g_seqT[T_SEQ*BATCH];  // [t][row]
__device__ __attribute__((aligned(128))) unsigned g_flags[16*32];    // 1 line/group

__device__ __forceinline__ rsrc_t mkrsrc(void* p){
  return __builtin_amdgcn_make_buffer_rsrc(p, (short)0, -1, 0x00020000);
}
__device__ __forceinline__ half8 ld_h8(rsrc_t r, int off){
  auto v = __builtin_amdgcn_raw_buffer_load_b128(r, off, 0, SCX);
  return __builtin_bit_cast(half8, v);
}
__device__ __forceinline__ floatx4 ld_f4(rsrc_t r, int off){
  auto v = __builtin_amdgcn_raw_buffer_load_b128(r, off, 0, SCX);
  return __builtin_bit_cast(floatx4, v);
}
__device__ __forceinline__ float ld_f(rsrc_t r, int off){
  auto v = __builtin_amdgcn_raw_buffer_load_b32(r, off, 0, SCX);
  return __builtin_bit_cast(float, v);
}
__device__ __forceinline__ void st_f(rsrc_t r, int off, float v){
  __builtin_amdgcn_raw_buffer_store_b32(__builtin_bit_cast(unsigned, v), r, off, 0, SCX);
}
__device__ __forceinline__ void st_f4(rsrc_t r, int off, floatx4 v){
  __builtin_amdgcn_raw_buffer_store_b128(v, r, off, 0, SCX);
}

// tanh for the cell-state nonlinearity (unchanged from r9/r11)
__device__ __forceinline__ float tanh_f(float x){
  return 1.0f - 2.0f*__builtin_amdgcn_rcpf(1.0f + __expf(2.0f*x));
}

// Release: drain stores (acked at own-XCD L2) + WG rendezvous, then wave-0
// lane-0 publishes the phase number at agent scope (LIC).
__device__ __forceinline__ void xsignal(int grp, int slot, unsigned target,
                                        int tid){
  __builtin_amdgcn_s_waitcnt(0);
  __syncthreads();
  if (tid == 0)
    __hip_atomic_store(&g_flags[grp*32 + slot], target, __ATOMIC_RELAXED,
                       __HIP_MEMORY_SCOPE_AGENT);
}

// Early sample of the group's flag line (wave 0 only). Issue point is
// before heavy compute -> the LIC round trip hides under it. Monotone
// flags make a stale sample safe (can only under-report).
__device__ __forceinline__ unsigned xsample(int grp, int tid){
  if (tid < 64)
    return __hip_atomic_load(&g_flags[grp*32 + (tid & 31)],
                             __ATOMIC_RELAXED, __HIP_MEMORY_SCOPE_AGENT);
  return 0u;
}

// Acquire with prefetched sample: if the early sample already satisfies
// the target, skip the poll entirely; else poll as before. Trailing
// __syncthreads releases the WG.
__device__ __forceinline__ void xwaitbar2(int grp, unsigned target,
                                          unsigned pre, bool& alive, int tid){
  if (tid < 64 && alive){
    if (__ballot(pre >= target) != 0xFFFFFFFFFFFFFFFFull){
      int guard = 0;
      for (;;){
        unsigned f = __hip_atomic_load(&g_flags[grp*32 + (tid & 31)],
                                       __ATOMIC_RELAXED, __HIP_MEMORY_SCOPE_AGENT);
        if (__ballot(f >= target) == 0xFFFFFFFFFFFFFFFFull) break;
        __builtin_amdgcn_s_sleep(1);
        if (++guard > (1<<22)){ alive = false; break; }
      }
    }
  }
  __syncthreads();
}

// Plain acquire (tail loops): wave 0 polls, trailing __syncthreads.
__device__ __forceinline__ void xwaitbar(int grp, unsigned target,
                                         bool& alive, int tid){
  if (tid < 64 && alive){
    int guard = 0;
    for (;;){
      unsigned f = __hip_atomic_load(&g_flags[grp*32 + (tid & 31)],
                                     __ATOMIC_RELAXED, __HIP_MEMORY_SCOPE_AGENT);
      if (__ballot(f >= target) == 0xFFFFFFFFFFFFFFFFull) break;
      __builtin_amdgcn_s_sleep(1);
      if (++guard > (1<<22)){ alive = false; break; }
    }
  }
  __syncthreads();
}

// One 16-row group phase. Stages group h slices L2->LDS (swizzled),
// MFMAs M=16 from LDS vs VGPR weights (split even/odd-kk chains, r11).
// Gate nonlinearity: single activation per lane (asc/ac0/ac1 select the
// lane's own gate form), activated values shuffled to lanes 0-3.
// DOL1: h1=lstm(x,h1prev); XSEL 0 = x from seqT, 1 = x from o-partial
// gather (+bl). DOL2: h2=lstm(h1r,h2prev) + 64B opart store.
template<bool DOL1, bool DOL2, int XSEL>
__device__ __forceinline__ void do_phase16(
    rsrc_t rh1, rsrc_t rh2, rsrc_t rop, rsrc_t rsq,
    int o_h1r, int o_h2r, int o_h1w, int o_h2w,
    int o_x, int xs_t, float xadd, int t_out,
    _Float16* __restrict__ lA1, _Float16* __restrict__ lA2,
    const half8 (&wf1)[16], const half8 (&wfx)[16], const half8 (&wfh)[16],
    float b1, float b2, float wx, float wl,
    float asc, float ac0, float ac1,
    float (&c1v)[4], float (&c2v)[4],
    int rowbase, int jbase, int jwave, int tid, int ln, int quad, int hcb)
{
  // ---- stage A slices (16 rows x 512 fp16) from L2 into swizzled LDS ----
  // gran = c16 + 16*g4 (r9): row's 16 lanes span all 8 LDS bank-groups.
  {
    const int row = tid >> 4, c16 = tid & 15;
    const int gb1 = o_h1r + (rowbase + row)*H*2;
    const int gb2 = o_h2r + (rowbase + row)*H*2;
    #pragma unroll
    for (int g4 = 0; g4 < 4; ++g4){
      const int gran = c16 + 16*g4;
      const int loff = row*512 + ((gran ^ (row&7)) << 3);
      half8 v = ld_h8(rh1, gb1 + gran*16);
      *(half8*)(lA1 + loff) = v;
      if (DOL2){
        half8 u = ld_h8(rh2, gb2 + gran*16);
        *(half8*)(lA2 + loff) = u;
      }
    }
  }

  float xv[4];
  if (DOL1){
    if (XSEL == 0){
      floatx4 x4 = ld_f4(rsq, o_x + (rowbase + quad*4)*4);
      #pragma unroll
      for (int r=0; r<4; ++r) xv[r] = x4[r] + xadd;
    } else {
      #pragma unroll
      for (int r=0; r<4; ++r){
        const int lr = quad*4 + r;            // group-local row
        float s = 0.f;
        #pragma unroll
        for (int cc=0; cc<8; ++cc){
          const int j = jbase + ln*8 + cc;    // 128 owners of this group
          s += ld_f(rop, ((j*TP + xs_t)*32 + lr)*4);
        }
        s += __shfl_xor(s, 1, 64);
        s += __shfl_xor(s, 2, 64);
        s += __shfl_xor(s, 4, 64);
        s += __shfl_xor(s, 8, 64);
        xv[r] = s + xadd;
      }
    }
  }
  __syncthreads();   // staging visible WG-wide

  floatx4 zf4 = {0.f,0.f,0.f,0.f};
  floatx4 z1a = zf4, z1b = zf4, z2a = zf4, z2b = zf4;

  #pragma unroll
  for (int kk = 0; kk < 16; kk += 2){
    const int sw0 = (((kk*4 + quad) ^ (ln&7)) << 3);
    const int sw1 = ((((kk+1)*4 + quad) ^ (ln&7)) << 3);
    half8 a1_0 = *(const half8*)(lA1 + ln*512 + sw0);
    half8 a1_1 = *(const half8*)(lA1 + ln*512 + sw1);
    if (DOL1){
      z1a = MFMA(a1_0, wf1[kk],   z1a);
      z1b = MFMA(a1_1, wf1[kk+1], z1b);
    }
    if (DOL2){
      z2a = MFMA(a1_0, wfx[kk],   z2a);
      z2b = MFMA(a1_1, wfx[kk+1], z2b);
      half8 a2_0 = *(const half8*)(lA2 + ln*512 + sw0);
      half8 a2_1 = *(const half8*)(lA2 + ln*512 + sw1);
      z2a = MFMA(a2_0, wfh[kk],   z2a);
      z2b = MFMA(a2_1, wfh[kk+1], z2b);
    }
  }
  floatx4 z1 = z1a + z1b;
  floatx4 z2 = z2a + z2b;

  const bool l4 = (ln < 4);
  const bool evn = ((ln & 1) == 0);
  if (DOL1){
    #pragma unroll
    for (int r=0; r<4; ++r){
      const int row = rowbase + quad*4 + r;
      float z = z1[r] + xv[r]*wx + b1;
      // own-gate activation: lanes ln<4 get ig; +4 -> fg, +8 -> og, +12 -> gg
      float t = __builtin_amdgcn_rcpf(1.0f + __expf(asc*z));
      float a = ac0 + ac1*t;
      float fg = __shfl_xor(a, 4, 64);
      float og = __shfl_xor(a, 8, 64);
      float gg = __shfl_xor(a, 12, 64);
      float c = fg*c1v[r] + a*gg;       // valid in lanes ln<4
      c1v[r] = c;
      float h = og*tanh_f(c);
      unsigned hu = (unsigned)__builtin_bit_cast(unsigned short, (_Float16)h);
      unsigned pn = (unsigned)__shfl_xor((int)hu, 1, 64);
      if (l4 && evn)
        st_f(rh1, o_h1w + (row*H + hcb + ln)*2,
             __builtin_bit_cast(float, hu | (pn<<16)));
    }
  }
  if (DOL2){
    floatx4 po4;
    #pragma unroll
    for (int r=0; r<4; ++r){
      const int row = rowbase + quad*4 + r;
      float z = z2[r] + b2;
      float t = __builtin_amdgcn_rcpf(1.0f + __expf(asc*z));
      float a = ac0 + ac1*t;
      float fg = __shfl_xor(a, 4, 64);
      float og = __shfl_xor(a, 8, 64);
      float gg = __shfl_xor(a, 12, 64);
      float c = fg*c2v[r] + a*gg;       // valid in lanes ln<4
      c2v[r] = c;
      float h = og*tanh_f(c);
      unsigned hu = (unsigned)__builtin_bit_cast(unsigned short, (_Float16)h);
      unsigned pn = (unsigned)__shfl_xor((int)hu, 1, 64);
      if (l4 && evn)
        st_f(rh2, o_h2w + (row*H + hcb + ln)*2,
             __builtin_bit_cast(float, hu | (pn<<16)));
      float po = l4 ? h*wl : 0.f;
      po += __shfl_xor(po, 1, 64);
      po += __shfl_xor(po, 2, 64);
      po4[r] = po;                  // valid in ln==0 lanes
    }
    if (ln == 0){                   // 64B line per wave per t (rows 0..15)
      const int base = ((jwave*TP + t_out)*32)*4;
      st_f4(rop, base + quad*16, po4);
    }
  }
}

__global__ void reset_kernel(){
  if (threadIdx.x < 16*32)
    __hip_atomic_store(&g_flags[threadIdx.x], 0u, __ATOMIC_RELAXED,
                       __HIP_MEMORY_SCOPE_AGENT);
}

__global__ __launch_bounds__(BLOCK, 1) void sinernn_kernel(
    const float* __restrict__ seq, const float* __restrict__ Wx1,
    const float* __restrict__ bx1, const float* __restrict__ Wh1,
    const float* __restrict__ bh1, const float* __restrict__ Wx2,
    const float* __restrict__ bx2, const float* __restrict__ Wh2,
    const float* __restrict__ bh2, const float* __restrict__ Wl,
    const float* __restrict__ bl,  float* __restrict__ out)
{
  __shared__ __attribute__((aligned(16))) _Float16 lA1A[RPG*512];  // 16 KB
  __shared__ __attribute__((aligned(16))) _Float16 lA2A[RPG*512];  // 16 KB
  __shared__ __attribute__((aligned(16))) _Float16 lA1B[RPG*512];  // 16 KB
  __shared__ __attribute__((aligned(16))) _Float16 lA2B[RPG*512];  // 16 KB

  const int tid  = threadIdx.x;
  const int wg   = blockIdx.x;
  const int xcd  = wg & 7;
  const int slot = wg >> 3;            // 0..31
  const int ga   = xcd, gb = xcd + 8;  // this WG's two groups
  const int w    = tid >> 6;
  const int lane = tid & 63;
  const int ln   = lane & 15;
  const int quad = lane >> 4;
  const int rbA  = ga*RPG, rbB = gb*RPG;
  const int hcb  = slot*16 + w*4;      // this wave's 4 h-cols
  const int jA   = ga*128 + slot*4 + w;
  const int jB   = gb*128 + slot*4 + w;

  rsrc_t rh1 = mkrsrc((void*)&g_h1[0]);
  rsrc_t rh2 = mkrsrc((void*)&g_h2[0]);
  rsrc_t rop = mkrsrc((void*)&g_opart[0]);
  rsrc_t rsq = mkrsrc((void*)&g_seqT[0]);

  // gate-col: gate = ln>>2, h-col = hcb + (ln&3)
  const int gc = (ln>>2)*H + hcb + (ln&3);
  // per-lane activation constants: gate 3 (g) uses tanh, others sigmoid
  const bool g3 = (ln>>2) == 3;
  const float asc = g3 ? 2.0f : -1.0f;
  const float ac0 = g3 ? 1.0f :  0.0f;
  const float ac1 = g3 ? -2.0f : 1.0f;

  // ---- prologue: seqT transpose (16 t-values x 16 rows x 2 groups) ----
  for (int i = tid; i < 2*16*16; i += BLOCK){
    int g = i >> 8;
    int t = slot*16 + ((i>>4)&15), j = i & 15;
    int row = (g ? rbB : rbA) + j;
    st_f(rsq, (t*BATCH + row)*4, seq[row*T_SEQ + t]);
  }
  // zero h(-1) (buffer 1) for both groups' rows; redundant across slots
  for (int i = tid; i < RPG*H/2; i += BLOCK){
    st_f(rh1, HBYTES + rbA*H*2 + i*4, 0.f);
    st_f(rh2, HBYTES + rbA*H*2 + i*4, 0.f);
    st_f(rh1, HBYTES + rbB*H*2 + i*4, 0.f);
    st_f(rh2, HBYTES + rbB*H*2 + i*4, 0.f);
  }

  // ---- stage all three weight slices into VGPRs (192/lane, shared) ----
  half8 wf1[16], wfx[16], wfh[16];
  #pragma unroll
  for (int kk = 0; kk < 16; ++kk){
    #pragma unroll
    for (int j = 0; j < 8; ++j){
      const int k = kk*32 + quad*8 + j;
      wf1[kk][j] = (_Float16)Wh1[k*G4H + gc];
      wfx[kk][j] = (_Float16)Wx2[k*G4H + gc];
      wfh[kk][j] = (_Float16)Wh2[k*G4H + gc];
    }
  }
  const float b1 = bx1[gc] + bh1[gc];
  const float b2 = bx2[gc] + bh2[gc];
  const float wx = Wx1[gc];
  const float wl = (ln < 4) ? Wl[hcb + (ln&3)] : 0.f;
  const float blv = bl[0];

  float c1A[4] = {0.f,0.f,0.f,0.f}, c2A[4] = {0.f,0.f,0.f,0.f};
  float c1B[4] = {0.f,0.f,0.f,0.f}, c2B[4] = {0.f,0.f,0.f,0.f};

  bool alive = true;
  unsigned cur = 1;
  xsignal(ga, slot, 1, tid);           // prologue visible group-wide
  xsignal(gb, slot, 1, tid);
  unsigned preA = xsample(ga, tid);    // early sample for round 0 waitA

  // ---- main: round p = {phaseA(p), phaseB(p)}; phase computes h1(p),h2(p-1)
  for (int p = 0; p < T_SEQ; ++p){
    const int b_h1r = ((p+1)&1)*HBYTES;
    const int b_h1w = (p&1)*HBYTES;
    const int b_h2r = (p&1)*HBYTES;
    const int b_h2w = ((p+1)&1)*HBYTES;

    xwaitbar2(ga, cur, preA, alive, tid);
    unsigned preB = xsample(gb, tid);   // RT hides under bodyA
    if (p == 0)
      do_phase16<true,false,0>(rh1,rh2,rop,rsq, b_h1r,0, b_h1w,0,
                               0, 0, 0.f, -1, lA1A, lA2A, wf1,wfx,wfh,
                               b1,b2,wx,wl, asc,ac0,ac1, c1A,c2A,
                               rbA, ga*128, jA, tid, ln, quad, hcb);
    else
      do_phase16<true,true,0>(rh1,rh2,rop,rsq, b_h1r,b_h2r, b_h1w,b_h2w,
                              p*BATCH*4, 0, 0.f, p-1, lA1A, lA2A, wf1,wfx,wfh,
                              b1,b2,wx,wl, asc,ac0,ac1, c1A,c2A,
                              rbA, ga*128, jA, tid, ln, quad, hcb);
    xsignal(ga, slot, cur+1, tid);

    xwaitbar2(gb, cur, preB, alive, tid);
    preA = xsample(ga, tid);            // RT hides under bodyB
    if (p == 0)
      do_phase16<true,false,0>(rh1,rh2,rop,rsq, b_h1r,0, b_h1w,0,
                               0, 0, 0.f, -1, lA1B, lA2B, wf1,wfx,wfh,
                               b1,b2,wx,wl, asc,ac0,ac1, c1B,c2B,
                               rbB, gb*128, jB, tid, ln, quad, hcb);
    else
      do_phase16<true,true,0>(rh1,rh2,rop,rsq, b_h1r,b_h2r, b_h1w,b_h2w,
                              p*BATCH*4, 0, 0.f, p-1, lA1B, lA2B, wf1,wfx,wfh,
                              b1,b2,wx,wl, asc,ac0,ac1, c1B,c2B,
                              rbB, gb*128, jB, tid, ln, quad, hcb);
    xsignal(gb, slot, cur+1, tid);
    ++cur;
  }

  // ---- drain + autoregressive predict (plain xbar; 11% of phases) ----
  for (int s = T_SEQ-1; s < TP; ++s){
    xwaitbar(ga, cur, alive, tid);
    do_phase16<false,true,0>(rh1,rh2,rop,rsq, (s&1)*HBYTES,((s+1)&1)*HBYTES,
                             0,(s&1)*HBYTES, 0, 0, 0.f, s,
                             lA1A, lA2A, wf1,wfx,wfh, b1,b2,wx,wl,
                             asc,ac0,ac1, c1A,c2A,
                             rbA, ga*128, jA, tid, ln, quad, hcb);
    xsignal(ga, slot, cur+1, tid);
    xwaitbar(gb, cur, alive, tid);
    do_phase16<false,true,0>(rh1,rh2,rop,rsq, (s&1)*HBYTES,((s+1)&1)*HBYTES,
                             0,(s&1)*HBYTES, 0, 0, 0.f, s,
                             lA1B, lA2B, wf1,wfx,wfh, b1,b2,wx,wl,
                             asc,ac0,ac1, c1B,c2B,
                             rbB, gb*128, jB, tid, ln, quad, hcb);
    xsignal(gb, slot, cur+1, tid);
    ++cur;

    if (s + 1 < TP){
      xwaitbar(ga, cur, alive, tid);
      do_phase16<true,false,1>(rh1,rh2,rop,rsq, (s&1)*HBYTES,0,
                               ((s+1)&1)*HBYTES,0, 0, s, blv, -1,
                               lA1A, lA2A, wf1,wfx,wfh, b1,b2,wx,wl,
                               asc,ac0,ac1, c1A,c2A,
                               rbA, ga*128, jA, tid, ln, quad, hcb);
      xsignal(ga, slot, cur+1, tid);
      xwaitbar(gb, cur, alive, tid);
      do_phase16<true,false,1>(rh1,rh2,rop,rsq, (s&1)*HBYTES,0,
                               ((s+1)&1)*HBYTES,0, 0, s, blv, -1,
                               lA1B, lA2B, wf1,wfx,wfh, b1,b2,wx,wl,
                               asc,ac0,ac1, c1B,c2B,
                               rbB, gb*128, jB, tid, ln, quad, hcb);
      xsignal(gb, slot, cur+1, tid);
      ++cur;
    }
  }
  xwaitbar(ga, cur, alive, tid);
  xwaitbar(gb, cur, alive, tid);

  // ---- epilogue: out[row][t] = sum over the group's 128 (slot',w') ----
  {
    float* lred = (float*)lA1A;          // reuse staging LDS
    const int row = tid & 15, part = tid >> 4;   // 16 parts x 8 j's
    for (int gsel = 0; gsel < 2; ++gsel){
      const int jb = (gsel ? gb : ga)*128;
      const int rb = (gsel ? rbB : rbA);
      for (int i = 0; i < 17; ++i){
        const int t = slot + i*32;
        float s = 0.f;
        #pragma unroll
        for (int q = 0; q < 8; ++q){
          const int j = jb + part*8 + q;
          s += ld_f(rop, ((j*TP + t)*32 + row)*4);
        }
        __syncthreads();
        lred[part*16 + row] = s;
        __syncthreads();
        if (tid < 16){
          float o = 0.f;
          #pragma unroll
          for (int p2 = 0; p2 < 16; ++p2) o += lred[p2*16 + tid];
          out[(rb + tid)*TP + t] = o + blv;
        }
      }
    }
  }
}

extern "C" void kernel_launch(void* const* d_in, const int* in_sizes, int n_in,
                              void* d_out, int out_size, void* d_ws, size_t ws_size,
                              hipStream_t stream) {
  const float* seq = (const float*)d_in[0];
  // d_in[1] = predict (=32, hardcoded)
  const float* Wx1 = (const float*)d_in[2];
  const float* bx1 = (const float*)d_in[3];
  const float* Wh1 = (const float*)d_in[4];
  const float* bh1 = (const float*)d_in[5];
  const float* Wx2 = (const float*)d_in[6];
  const float* bx2 = (const float*)d_in[7];
  const float* Wh2 = (const float*)d_in[8];
  const float* bh2 = (const float*)d_in[9];
  const float* Wl  = (const float*)d_in[10];
  const float* bl  = (const float*)d_in[11];
  float* out = (float*)d_out;

  reset_kernel<<<1, 512, 0, stream>>>();

  sinernn_kernel<<<dim3(GRID), dim3(BLOCK), 0, stream>>>(
      seq, Wx1, bx1, Wh1, bh1, Wx2, bx2, Wh2, bh2, Wl, bl, out);
}

// Round 13
// 4834.712 us; speedup vs baseline: 1.1251x; 1.1251x over previous
//
#include <hip/hip_runtime.h>

// ---------------- problem constants ----------------
#define T_SEQ 512
#define P_PRED 32
#define TP 544            // T_SEQ + P_PRED
#define BATCH 256
#define H 512
#define G4H 2048
// ---------------- kernel config --------------------
// ROUND-13 = ROUND-11 (best, 4129us) + SINGLE-ACTIVATION-PER-LANE ONLY
// (isolating r12's lever 1; r12's flag-prefetch lever is DROPPED — r12
// bundled both and regressed 4129->5440 with a stall signature).
// Lane ln holds gate ln>>2's pre-activation; it applies its OWN gate's
// nonlinearity (unified a = ac0 + ac1*rcp(1+exp(asc*z))), then ACTIVATED
// values are shuffled to the consumer lanes. Consumed lanes (ln<4) see
// bit-identical math to r11; cuts 4 exp+4 rcp to 1+1 per gate value
// (r12 counters confirmed the cut: -28% VALU cycles).
// All r11 invariants kept: 16 groups of 16 rows, group g on XCD g&7;
// 256 WGs = 8 XCDs x 32 slots; WG serves groups xcd, xcd+8 per round
// (age-1 A/B pipelining); weights in VGPRs (192/lane, 1 wave/SIMD
// mandatory - r8); flags agent-scope LIC atomics ONLY (r6+r10); data SC0
// at XCD L2 (r4); rcp activations (r9); conflict-free staging gran (r9);
// split MFMA chains (r11); r11's plain xsignal/xwaitbar everywhere.
// Tripwires: dur>=4250 or absmax fail -> lever 1 is the poison -> r11
// is the final kernel.
#define GRID 256
#define BLOCK 256
#define RPG 16              // rows per group
#define HBUF (BATCH*H)      // elements per h double-buffer slot
#define HBYTES (HBUF*2)
#define SCX 1               // CPol: SC0 -> bypass L1, coherent at XCD L2

typedef _Float16 half8 __attribute__((ext_vector_type(8)));
typedef float floatx4 __attribute__((ext_vector_type(4)));
typedef __amdgpu_buffer_rsrc_t rsrc_t;

#define MFMA(a,b,c) __builtin_amdgcn_mfma_f32_16x16x32_f16((a),(b),(c),0,0,0)

// ---------------- device-global state --------------
__device__ __attribute__((aligned(128))) _Float16 g_h1[2*HBUF];
__device__ __attribute__((aligned(128))) _Float16 g_h2[2*HBUF];
// o partials: [j = g*128 + slot*4 + w][t][32 slots (16 rows used)]
__device__ __attribute__((aligned(128))) float g_opart[(size_t)2048*TP*32];
__device__ __attribute__((aligned(128))) float g_seqT[T_SEQ*BATCH];  // [t][row]
__device__ __attribute__((aligned(128))) unsigned g_flags[16*32];    // 1 line/group

__device__ __forceinline__ rsrc_t mkrsrc(void* p){
  return __builtin_amdgcn_make_buffer_rsrc(p, (short)0, -1, 0x00020000);
}
__device__ __forceinline__ half8 ld_h8(rsrc_t r, int off){
  auto v = __builtin_amdgcn_raw_buffer_load_b128(r, off, 0, SCX);
  return __builtin_bit_cast(half8, v);
}
__device__ __forceinline__ floatx4 ld_f4(rsrc_t r, int off){
  auto v = __builtin_amdgcn_raw_buffer_load_b128(r, off, 0, SCX);
  return __builtin_bit_cast(floatx4, v);
}
__device__ __forceinline__ float ld_f(rsrc_t r, int off){
  auto v = __builtin_amdgcn_raw_buffer_load_b32(r, off, 0, SCX);
  return __builtin_bit_cast(float, v);
}
__device__ __forceinline__ void st_f(rsrc_t r, int off, float v){
  __builtin_amdgcn_raw_buffer_store_b32(__builtin_bit_cast(unsigned, v), r, off, 0, SCX);
}
__device__ __forceinline__ void st_f4(rsrc_t r, int off, floatx4 v){
  __builtin_amdgcn_raw_buffer_store_b128(v, r, off, 0, SCX);
}

// tanh for the cell-state nonlinearity (unchanged from r9/r11)
__device__ __forceinline__ float tanh_f(float x){
  return 1.0f - 2.0f*__builtin_amdgcn_rcpf(1.0f + __expf(2.0f*x));
}

// Release: drain stores (acked at own-XCD L2) + WG rendezvous, then wave-0
// lane-0 publishes the phase number at agent scope (LIC).
__device__ __forceinline__ void xsignal(int grp, int slot, unsigned target,
                                        int tid){
  __builtin_amdgcn_s_waitcnt(0);
  __syncthreads();
  if (tid == 0)
    __hip_atomic_store(&g_flags[grp*32 + slot], target, __ATOMIC_RELAXED,
                       __HIP_MEMORY_SCOPE_AGENT);
}

// Acquire: wave 0 polls the group's 32-slot flag line (lane&31), trailing
// __syncthreads releases the WG. Monotone phases, spin guard.
__device__ __forceinline__ void xwaitbar(int grp, unsigned target,
                                         bool& alive, int tid){
  if (tid < 64 && alive){
    int guard = 0;
    for (;;){
      unsigned f = __hip_atomic_load(&g_flags[grp*32 + (tid & 31)],
                                     __ATOMIC_RELAXED, __HIP_MEMORY_SCOPE_AGENT);
      if (__ballot(f >= target) == 0xFFFFFFFFFFFFFFFFull) break;
      __builtin_amdgcn_s_sleep(1);
      if (++guard > (1<<22)){ alive = false; break; }
    }
  }
  __syncthreads();
}

// One 16-row group phase. Stages group h slices L2->LDS (swizzled),
// MFMAs M=16 from LDS vs VGPR weights (split even/odd-kk chains, r11).
// Gate nonlinearity: single activation per lane (asc/ac0/ac1 select the
// lane's own gate form), activated values shuffled to lanes 0-3.
// DOL1: h1=lstm(x,h1prev); XSEL 0 = x from seqT, 1 = x from o-partial
// gather (+bl). DOL2: h2=lstm(h1r,h2prev) + 64B opart store.
template<bool DOL1, bool DOL2, int XSEL>
__device__ __forceinline__ void do_phase16(
    rsrc_t rh1, rsrc_t rh2, rsrc_t rop, rsrc_t rsq,
    int o_h1r, int o_h2r, int o_h1w, int o_h2w,
    int o_x, int xs_t, float xadd, int t_out,
    _Float16* __restrict__ lA1, _Float16* __restrict__ lA2,
    const half8 (&wf1)[16], const half8 (&wfx)[16], const half8 (&wfh)[16],
    float b1, float b2, float wx, float wl,
    float asc, float ac0, float ac1,
    float (&c1v)[4], float (&c2v)[4],
    int rowbase, int jbase, int jwave, int tid, int ln, int quad, int hcb)
{
  // ---- stage A slices (16 rows x 512 fp16) from L2 into swizzled LDS ----
  // gran = c16 + 16*g4 (r9): row's 16 lanes span all 8 LDS bank-groups.
  {
    const int row = tid >> 4, c16 = tid & 15;
    const int gb1 = o_h1r + (rowbase + row)*H*2;
    const int gb2 = o_h2r + (rowbase + row)*H*2;
    #pragma unroll
    for (int g4 = 0; g4 < 4; ++g4){
      const int gran = c16 + 16*g4;
      const int loff = row*512 + ((gran ^ (row&7)) << 3);
      half8 v = ld_h8(rh1, gb1 + gran*16);
      *(half8*)(lA1 + loff) = v;
      if (DOL2){
        half8 u = ld_h8(rh2, gb2 + gran*16);
        *(half8*)(lA2 + loff) = u;
      }
    }
  }

  float xv[4];
  if (DOL1){
    if (XSEL == 0){
      floatx4 x4 = ld_f4(rsq, o_x + (rowbase + quad*4)*4);
      #pragma unroll
      for (int r=0; r<4; ++r) xv[r] = x4[r] + xadd;
    } else {
      #pragma unroll
      for (int r=0; r<4; ++r){
        const int lr = quad*4 + r;            // group-local row
        float s = 0.f;
        #pragma unroll
        for (int cc=0; cc<8; ++cc){
          const int j = jbase + ln*8 + cc;    // 128 owners of this group
          s += ld_f(rop, ((j*TP + xs_t)*32 + lr)*4);
        }
        s += __shfl_xor(s, 1, 64);
        s += __shfl_xor(s, 2, 64);
        s += __shfl_xor(s, 4, 64);
        s += __shfl_xor(s, 8, 64);
        xv[r] = s + xadd;
      }
    }
  }
  __syncthreads();   // staging visible WG-wide

  floatx4 zf4 = {0.f,0.f,0.f,0.f};
  floatx4 z1a = zf4, z1b = zf4, z2a = zf4, z2b = zf4;

  #pragma unroll
  for (int kk = 0; kk < 16; kk += 2){
    const int sw0 = (((kk*4 + quad) ^ (ln&7)) << 3);
    const int sw1 = ((((kk+1)*4 + quad) ^ (ln&7)) << 3);
    half8 a1_0 = *(const half8*)(lA1 + ln*512 + sw0);
    half8 a1_1 = *(const half8*)(lA1 + ln*512 + sw1);
    if (DOL1){
      z1a = MFMA(a1_0, wf1[kk],   z1a);
      z1b = MFMA(a1_1, wf1[kk+1], z1b);
    }
    if (DOL2){
      z2a = MFMA(a1_0, wfx[kk],   z2a);
      z2b = MFMA(a1_1, wfx[kk+1], z2b);
      half8 a2_0 = *(const half8*)(lA2 + ln*512 + sw0);
      half8 a2_1 = *(const half8*)(lA2 + ln*512 + sw1);
      z2a = MFMA(a2_0, wfh[kk],   z2a);
      z2b = MFMA(a2_1, wfh[kk+1], z2b);
    }
  }
  floatx4 z1 = z1a + z1b;
  floatx4 z2 = z2a + z2b;

  const bool l4 = (ln < 4);
  const bool evn = ((ln & 1) == 0);
  if (DOL1){
    #pragma unroll
    for (int r=0; r<4; ++r){
      const int row = rowbase + quad*4 + r;
      float z = z1[r] + xv[r]*wx + b1;
      // own-gate activation: lanes ln<4 get ig; +4 -> fg, +8 -> og, +12 -> gg
      float t = __builtin_amdgcn_rcpf(1.0f + __expf(asc*z));
      float a = ac0 + ac1*t;
      float fg = __shfl_xor(a, 4, 64);
      float og = __shfl_xor(a, 8, 64);
      float gg = __shfl_xor(a, 12, 64);
      float c = fg*c1v[r] + a*gg;       // valid in lanes ln<4
      c1v[r] = c;
      float h = og*tanh_f(c);
      unsigned hu = (unsigned)__builtin_bit_cast(unsigned short, (_Float16)h);
      unsigned pn = (unsigned)__shfl_xor((int)hu, 1, 64);
      if (l4 && evn)
        st_f(rh1, o_h1w + (row*H + hcb + ln)*2,
             __builtin_bit_cast(float, hu | (pn<<16)));
    }
  }
  if (DOL2){
    floatx4 po4;
    #pragma unroll
    for (int r=0; r<4; ++r){
      const int row = rowbase + quad*4 + r;
      float z = z2[r] + b2;
      float t = __builtin_amdgcn_rcpf(1.0f + __expf(asc*z));
      float a = ac0 + ac1*t;
      float fg = __shfl_xor(a, 4, 64);
      float og = __shfl_xor(a, 8, 64);
      float gg = __shfl_xor(a, 12, 64);
      float c = fg*c2v[r] + a*gg;       // valid in lanes ln<4
      c2v[r] = c;
      float h = og*tanh_f(c);
      unsigned hu = (unsigned)__builtin_bit_cast(unsigned short, (_Float16)h);
      unsigned pn = (unsigned)__shfl_xor((int)hu, 1, 64);
      if (l4 && evn)
        st_f(rh2, o_h2w + (row*H + hcb + ln)*2,
             __builtin_bit_cast(float, hu | (pn<<16)));
      float po = l4 ? h*wl : 0.f;
      po += __shfl_xor(po, 1, 64);
      po += __shfl_xor(po, 2, 64);
      po4[r] = po;                  // valid in ln==0 lanes
    }
    if (ln == 0){                   // 64B line per wave per t (rows 0..15)
      const int base = ((jwave*TP + t_out)*32)*4;
      st_f4(rop, base + quad*16, po4);
    }
  }
}

__global__ void reset_kernel(){
  if (threadIdx.x < 16*32)
    __hip_atomic_store(&g_flags[threadIdx.x], 0u, __ATOMIC_RELAXED,
                       __HIP_MEMORY_SCOPE_AGENT);
}

__global__ __launch_bounds__(BLOCK, 1) void sinernn_kernel(
    const float* __restrict__ seq, const float* __restrict__ Wx1,
    const float* __restrict__ bx1, const float* __restrict__ Wh1,
    const float* __restrict__ bh1, const float* __restrict__ Wx2,
    const float* __restrict__ bx2, const float* __restrict__ Wh2,
    const float* __restrict__ bh2, const float* __restrict__ Wl,
    const float* __restrict__ bl,  float* __restrict__ out)
{
  __shared__ __attribute__((aligned(16))) _Float16 lA1A[RPG*512];  // 16 KB
  __shared__ __attribute__((aligned(16))) _Float16 lA2A[RPG*512];  // 16 KB
  __shared__ __attribute__((aligned(16))) _Float16 lA1B[RPG*512];  // 16 KB
  __shared__ __attribute__((aligned(16))) _Float16 lA2B[RPG*512];  // 16 KB

  const int tid  = threadIdx.x;
  const int wg   = blockIdx.x;
  const int xcd  = wg & 7;
  const int slot = wg >> 3;            // 0..31
  const int ga   = xcd, gb = xcd + 8;  // this WG's two groups
  const int w    = tid >> 6;
  const int lane = tid & 63;
  const int ln   = lane & 15;
  const int quad = lane >> 4;
  const int rbA  = ga*RPG, rbB = gb*RPG;
  const int hcb  = slot*16 + w*4;      // this wave's 4 h-cols
  const int jA   = ga*128 + slot*4 + w;
  const int jB   = gb*128 + slot*4 + w;

  rsrc_t rh1 = mkrsrc((void*)&g_h1[0]);
  rsrc_t rh2 = mkrsrc((void*)&g_h2[0]);
  rsrc_t rop = mkrsrc((void*)&g_opart[0]);
  rsrc_t rsq = mkrsrc((void*)&g_seqT[0]);

  // gate-col: gate = ln>>2, h-col = hcb + (ln&3)
  const int gc = (ln>>2)*H + hcb + (ln&3);
  // per-lane activation constants: gate 3 (g) uses tanh, others sigmoid
  const bool g3 = (ln>>2) == 3;
  const float asc = g3 ? 2.0f : -1.0f;
  const float ac0 = g3 ? 1.0f :  0.0f;
  const float ac1 = g3 ? -2.0f : 1.0f;

  // ---- prologue: seqT transpose (16 t-values x 16 rows x 2 groups) ----
  for (int i = tid; i < 2*16*16; i += BLOCK){
    int g = i >> 8;
    int t = slot*16 + ((i>>4)&15), j = i & 15;
    int row = (g ? rbB : rbA) + j;
    st_f(rsq, (t*BATCH + row)*4, seq[row*T_SEQ + t]);
  }
  // zero h(-1) (buffer 1) for both groups' rows; redundant across slots
  for (int i = tid; i < RPG*H/2; i += BLOCK){
    st_f(rh1, HBYTES + rbA*H*2 + i*4, 0.f);
    st_f(rh2, HBYTES + rbA*H*2 + i*4, 0.f);
    st_f(rh1, HBYTES + rbB*H*2 + i*4, 0.f);
    st_f(rh2, HBYTES + rbB*H*2 + i*4, 0.f);
  }

  // ---- stage all three weight slices into VGPRs (192/lane, shared) ----
  half8 wf1[16], wfx[16], wfh[16];
  #pragma unroll
  for (int kk = 0; kk < 16; ++kk){
    #pragma unroll
    for (int j = 0; j < 8; ++j){
      const int k = kk*32 + quad*8 + j;
      wf1[kk][j] = (_Float16)Wh1[k*G4H + gc];
      wfx[kk][j] = (_Float16)Wx2[k*G4H + gc];
      wfh[kk][j] = (_Float16)Wh2[k*G4H + gc];
    }
  }
  const float b1 = bx1[gc] + bh1[gc];
  const float b2 = bx2[gc] + bh2[gc];
  const float wx = Wx1[gc];
  const float wl = (ln < 4) ? Wl[hcb + (ln&3)] : 0.f;
  const float blv = bl[0];

  float c1A[4] = {0.f,0.f,0.f,0.f}, c2A[4] = {0.f,0.f,0.f,0.f};
  float c1B[4] = {0.f,0.f,0.f,0.f}, c2B[4] = {0.f,0.f,0.f,0.f};

  bool alive = true;
  unsigned cur = 1;
  xsignal(ga, slot, 1, tid);           // prologue visible group-wide
  xsignal(gb, slot, 1, tid);

  // ---- main: round p = {phaseA(p), phaseB(p)}; phase computes h1(p),h2(p-1)
  for (int p = 0; p < T_SEQ; ++p){
    const int b_h1r = ((p+1)&1)*HBYTES;
    const int b_h1w = (p&1)*HBYTES;
    const int b_h2r = (p&1)*HBYTES;
    const int b_h2w = ((p+1)&1)*HBYTES;

    xwaitbar(ga, cur, alive, tid);
    if (p == 0)
      do_phase16<true,false,0>(rh1,rh2,rop,rsq, b_h1r,0, b_h1w,0,
                               0, 0, 0.f, -1, lA1A, lA2A, wf1,wfx,wfh,
                               b1,b2,wx,wl, asc,ac0,ac1, c1A,c2A,
                               rbA, ga*128, jA, tid, ln, quad, hcb);
    else
      do_phase16<true,true,0>(rh1,rh2,rop,rsq, b_h1r,b_h2r, b_h1w,b_h2w,
                              p*BATCH*4, 0, 0.f, p-1, lA1A, lA2A, wf1,wfx,wfh,
                              b1,b2,wx,wl, asc,ac0,ac1, c1A,c2A,
                              rbA, ga*128, jA, tid, ln, quad, hcb);
    xsignal(ga, slot, cur+1, tid);

    xwaitbar(gb, cur, alive, tid);
    if (p == 0)
      do_phase16<true,false,0>(rh1,rh2,rop,rsq, b_h1r,0, b_h1w,0,
                               0, 0, 0.f, -1, lA1B, lA2B, wf1,wfx,wfh,
                               b1,b2,wx,wl, asc,ac0,ac1, c1B,c2B,
                               rbB, gb*128, jB, tid, ln, quad, hcb);
    else
      do_phase16<true,true,0>(rh1,rh2,rop,rsq, b_h1r,b_h2r, b_h1w,b_h2w,
                              p*BATCH*4, 0, 0.f, p-1, lA1B, lA2B, wf1,wfx,wfh,
                              b1,b2,wx,wl, asc,ac0,ac1, c1B,c2B,
                              rbB, gb*128, jB, tid, ln, quad, hcb);
    xsignal(gb, slot, cur+1, tid);
    ++cur;
  }

  // ---- drain + autoregressive predict (one phase per group per round) ----
  for (int s = T_SEQ-1; s < TP; ++s){
    xwaitbar(ga, cur, alive, tid);
    do_phase16<false,true,0>(rh1,rh2,rop,rsq, (s&1)*HBYTES,((s+1)&1)*HBYTES,
                             0,(s&1)*HBYTES, 0, 0, 0.f, s,
                             lA1A, lA2A, wf1,wfx,wfh, b1,b2,wx,wl,
                             asc,ac0,ac1, c1A,c2A,
                             rbA, ga*128, jA, tid, ln, quad, hcb);
    xsignal(ga, slot, cur+1, tid);
    xwaitbar(gb, cur, alive, tid);
    do_phase16<false,true,0>(rh1,rh2,rop,rsq, (s&1)*HBYTES,((s+1)&1)*HBYTES,
                             0,(s&1)*HBYTES, 0, 0, 0.f, s,
                             lA1B, lA2B, wf1,wfx,wfh, b1,b2,wx,wl,
                             asc,ac0,ac1, c1B,c2B,
                             rbB, gb*128, jB, tid, ln, quad, hcb);
    xsignal(gb, slot, cur+1, tid);
    ++cur;

    if (s + 1 < TP){
      xwaitbar(ga, cur, alive, tid);
      do_phase16<true,false,1>(rh1,rh2,rop,rsq, (s&1)*HBYTES,0,
                               ((s+1)&1)*HBYTES,0, 0, s, blv, -1,
                               lA1A, lA2A, wf1,wfx,wfh, b1,b2,wx,wl,
                               asc,ac0,ac1, c1A,c2A,
                               rbA, ga*128, jA, tid, ln, quad, hcb);
      xsignal(ga, slot, cur+1, tid);
      xwaitbar(gb, cur, alive, tid);
      do_phase16<true,false,1>(rh1,rh2,rop,rsq, (s&1)*HBYTES,0,
                               ((s+1)&1)*HBYTES,0, 0, s, blv, -1,
                               lA1B, lA2B, wf1,wfx,wfh, b1,b2,wx,wl,
                               asc,ac0,ac1, c1B,c2B,
                               rbB, gb*128, jB, tid, ln, quad, hcb);
      xsignal(gb, slot, cur+1, tid);
      ++cur;
    }
  }
  xwaitbar(ga, cur, alive, tid);
  xwaitbar(gb, cur, alive, tid);

  // ---- epilogue: out[row][t] = sum over the group's 128 (slot',w') ----
  {
    float* lred = (float*)lA1A;          // reuse staging LDS
    const int row = tid & 15, part = tid >> 4;   // 16 parts x 8 j's
    for (int gsel = 0; gsel < 2; ++gsel){
      const int jb = (gsel ? gb : ga)*128;
      const int rb = (gsel ? rbB : rbA);
      for (int i = 0; i < 17; ++i){
        const int t = slot + i*32;
        float s = 0.f;
        #pragma unroll
        for (int q = 0; q < 8; ++q){
          const int j = jb + part*8 + q;
          s += ld_f(rop, ((j*TP + t)*32 + row)*4);
        }
        __syncthreads();
        lred[part*16 + row] = s;
        __syncthreads();
        if (tid < 16){
          float o = 0.f;
          #pragma unroll
          for (int p2 = 0; p2 < 16; ++p2) o += lred[p2*16 + tid];
          out[(rb + tid)*TP + t] = o + blv;
        }
      }
    }
  }
}

extern "C" void kernel_launch(void* const* d_in, const int* in_sizes, int n_in,
                              void* d_out, int out_size, void* d_ws, size_t ws_size,
                              hipStream_t stream) {
  const float* seq = (const float*)d_in[0];
  // d_in[1] = predict (=32, hardcoded)
  const float* Wx1 = (const float*)d_in[2];
  const float* bx1 = (const float*)d_in[3];
  const float* Wh1 = (const float*)d_in[4];
  const float* bh1 = (const float*)d_in[5];
  const float* Wx2 = (const float*)d_in[6];
  const float* bx2 = (const float*)d_in[7];
  const float* Wh2 = (const float*)d_in[8];
  const float* bh2 = (const float*)d_in[9];
  const float* Wl  = (const float*)d_in[10];
  const float* bl  = (const float*)d_in[11];
  float* out = (float*)d_out;

  reset_kernel<<<1, 512, 0, stream>>>();

  sinernn_kernel<<<dim3(GRID), dim3(BLOCK), 0, stream>>>(
      seq, Wx1, bx1, Wh1, bh1, Wx2, bx2, Wh2, bh2, Wl, bl, out);
}

// Round 14
// 4233.036 us; speedup vs baseline: 1.2850x; 1.1421x over previous
//
#include <hip/hip_runtime.h>

// ---------------- problem constants ----------------
#define T_SEQ 512
#define P_PRED 32
#define TP 544            // T_SEQ + P_PRED
#define BATCH 256
#define H 512
#define G4H 2048
// ---------------- kernel config --------------------
// ROUND-14 = ROUND-11 (best, 4129us) + z2 4-WAY MFMA CHAIN SPLIT ONLY.
// r12/r13 proved the body is dependency-latency-bound: instruction cuts
// that lengthen serial chains (activation-before-shuffle) regress; chain
// splits (r11: 32->16 deep, +120us) win. This round: z2's two 16-deep
// chains -> four 8-deep chains (z2a..z2d; a1-products and a2-products in
// separate accumulators), matching z1's 8-deep. +8 VGPR, +2 vector adds.
// ALL other code byte-identical to r11: activations in the parallel-
// redundant form (4 per lane AFTER shuffles - latency-optimal, r13 proved
// the "optimized" form is slower); 16 groups of 16 rows, group g on XCD
// g&7; 256 WGs = 8 XCDs x 32 slots; WG serves groups xcd, xcd+8 per round
// (age-1 A/B pipelining); weights in VGPRs (192/lane, 1 wave/SIMD
// mandatory - r8); flags agent-scope LIC atomics ONLY (r6+r10 proved SC0
// flags unsound); data SC0 at XCD L2 (r4); rcp activations (r9);
// conflict-free staging gran (r9).
// Tripwires: dur>=4150 or absmax fail -> r11 is the final kernel.
#define GRID 256
#define BLOCK 256
#define RPG 16              // rows per group
#define HBUF (BATCH*H)      // elements per h double-buffer slot
#define HBYTES (HBUF*2)
#define SCX 1               // CPol: SC0 -> bypass L1, coherent at XCD L2

typedef _Float16 half8 __attribute__((ext_vector_type(8)));
typedef float floatx4 __attribute__((ext_vector_type(4)));
typedef __amdgpu_buffer_rsrc_t rsrc_t;

#define MFMA(a,b,c) __builtin_amdgcn_mfma_f32_16x16x32_f16((a),(b),(c),0,0,0)

// ---------------- device-global state --------------
__device__ __attribute__((aligned(128))) _Float16 g_h1[2*HBUF];
__device__ __attribute__((aligned(128))) _Float16 g_h2[2*HBUF];
// o partials: [j = g*128 + slot*4 + w][t][32 slots (16 rows used)]
__device__ __attribute__((aligned(128))) float g_opart[(size_t)2048*TP*32];
__device__ __attribute__((aligned(128))) float g_seqT[T_SEQ*BATCH];  // [t][row]
__device__ __attribute__((aligned(128))) unsigned g_flags[16*32];    // 1 line/group

__device__ __forceinline__ rsrc_t mkrsrc(void* p){
  return __builtin_amdgcn_make_buffer_rsrc(p, (short)0, -1, 0x00020000);
}
__device__ __forceinline__ half8 ld_h8(rsrc_t r, int off){
  auto v = __builtin_amdgcn_raw_buffer_load_b128(r, off, 0, SCX);
  return __builtin_bit_cast(half8, v);
}
__device__ __forceinline__ floatx4 ld_f4(rsrc_t r, int off){
  auto v = __builtin_amdgcn_raw_buffer_load_b128(r, off, 0, SCX);
  return __builtin_bit_cast(floatx4, v);
}
__device__ __forceinline__ float ld_f(rsrc_t r, int off){
  auto v = __builtin_amdgcn_raw_buffer_load_b32(r, off, 0, SCX);
  return __builtin_bit_cast(float, v);
}
__device__ __forceinline__ void st_f(rsrc_t r, int off, float v){
  __builtin_amdgcn_raw_buffer_store_b32(__builtin_bit_cast(unsigned, v), r, off, 0, SCX);
}
__device__ __forceinline__ void st_f4(rsrc_t r, int off, floatx4 v){
  __builtin_amdgcn_raw_buffer_store_b128(v, r, off, 0, SCX);
}

// Fast activations: v_rcp_f32 (~1 ulp) instead of precise div (r9-proven).
__device__ __forceinline__ float sigm(float x){
  return __builtin_amdgcn_rcpf(1.0f + __expf(-x));
}
__device__ __forceinline__ float tanh_f(float x){
  return 1.0f - 2.0f*__builtin_amdgcn_rcpf(1.0f + __expf(2.0f*x));
}

// Release: drain stores (acked at own-XCD L2) + WG rendezvous, then wave-0
// lane-0 publishes the phase number at agent scope (LIC).
__device__ __forceinline__ void xsignal(int grp, int slot, unsigned target,
                                        int tid){
  __builtin_amdgcn_s_waitcnt(0);
  __syncthreads();
  if (tid == 0)
    __hip_atomic_store(&g_flags[grp*32 + slot], target, __ATOMIC_RELAXED,
                       __HIP_MEMORY_SCOPE_AGENT);
}

// Acquire: wave 0 polls the group's 32-slot flag line (lane&31), trailing
// __syncthreads releases the WG. Monotone phases, spin guard.
__device__ __forceinline__ void xwaitbar(int grp, unsigned target,
                                         bool& alive, int tid){
  if (tid < 64 && alive){
    int guard = 0;
    for (;;){
      unsigned f = __hip_atomic_load(&g_flags[grp*32 + (tid & 31)],
                                     __ATOMIC_RELAXED, __HIP_MEMORY_SCOPE_AGENT);
      if (__ballot(f >= target) == 0xFFFFFFFFFFFFFFFFull) break;
      __builtin_amdgcn_s_sleep(1);
      if (++guard > (1<<22)){ alive = false; break; }
    }
  }
  __syncthreads();
}

// One 16-row group phase. Stages group h slices L2->LDS (swizzled),
// MFMAs M=16 from LDS vs VGPR weights (z1: 2x8-deep, z2: 4x8-deep chains).
// DOL1: h1=lstm(x,h1prev); XSEL 0 = x from seqT, 1 = x from o-partial
// gather (+bl). DOL2: h2=lstm(h1r,h2prev) + 64B opart store.
template<bool DOL1, bool DOL2, int XSEL>
__device__ __forceinline__ void do_phase16(
    rsrc_t rh1, rsrc_t rh2, rsrc_t rop, rsrc_t rsq,
    int o_h1r, int o_h2r, int o_h1w, int o_h2w,
    int o_x, int xs_t, float xadd, int t_out,
    _Float16* __restrict__ lA1, _Float16* __restrict__ lA2,
    const half8 (&wf1)[16], const half8 (&wfx)[16], const half8 (&wfh)[16],
    float b1, float b2, float wx, float wl,
    float (&c1v)[4], float (&c2v)[4],
    int rowbase, int jbase, int jwave, int tid, int ln, int quad, int hcb)
{
  // ---- stage A slices (16 rows x 512 fp16) from L2 into swizzled LDS ----
  // gran = c16 + 16*g4 (r9): row's 16 lanes span all 8 LDS bank-groups.
  {
    const int row = tid >> 4, c16 = tid & 15;
    const int gb1 = o_h1r + (rowbase + row)*H*2;
    const int gb2 = o_h2r + (rowbase + row)*H*2;
    #pragma unroll
    for (int g4 = 0; g4 < 4; ++g4){
      const int gran = c16 + 16*g4;
      const int loff = row*512 + ((gran ^ (row&7)) << 3);
      half8 v = ld_h8(rh1, gb1 + gran*16);
      *(half8*)(lA1 + loff) = v;
      if (DOL2){
        half8 u = ld_h8(rh2, gb2 + gran*16);
        *(half8*)(lA2 + loff) = u;
      }
    }
  }

  float xv[4];
  if (DOL1){
    if (XSEL == 0){
      floatx4 x4 = ld_f4(rsq, o_x + (rowbase + quad*4)*4);
      #pragma unroll
      for (int r=0; r<4; ++r) xv[r] = x4[r] + xadd;
    } else {
      #pragma unroll
      for (int r=0; r<4; ++r){
        const int lr = quad*4 + r;            // group-local row
        float s = 0.f;
        #pragma unroll
        for (int cc=0; cc<8; ++cc){
          const int j = jbase + ln*8 + cc;    // 128 owners of this group
          s += ld_f(rop, ((j*TP + xs_t)*32 + lr)*4);
        }
        s += __shfl_xor(s, 1, 64);
        s += __shfl_xor(s, 2, 64);
        s += __shfl_xor(s, 4, 64);
        s += __shfl_xor(s, 8, 64);
        xv[r] = s + xadd;
      }
    }
  }
  __syncthreads();   // staging visible WG-wide

  floatx4 zf4 = {0.f,0.f,0.f,0.f};
  floatx4 z1a = zf4, z1b = zf4;
  floatx4 z2a = zf4, z2b = zf4, z2c = zf4, z2d = zf4;

  #pragma unroll
  for (int kk = 0; kk < 16; kk += 2){
    const int sw0 = (((kk*4 + quad) ^ (ln&7)) << 3);
    const int sw1 = ((((kk+1)*4 + quad) ^ (ln&7)) << 3);
    half8 a1_0 = *(const half8*)(lA1 + ln*512 + sw0);
    half8 a1_1 = *(const half8*)(lA1 + ln*512 + sw1);
    if (DOL1){
      z1a = MFMA(a1_0, wf1[kk],   z1a);
      z1b = MFMA(a1_1, wf1[kk+1], z1b);
    }
    if (DOL2){
      z2a = MFMA(a1_0, wfx[kk],   z2a);
      z2b = MFMA(a1_1, wfx[kk+1], z2b);
      half8 a2_0 = *(const half8*)(lA2 + ln*512 + sw0);
      half8 a2_1 = *(const half8*)(lA2 + ln*512 + sw1);
      z2c = MFMA(a2_0, wfh[kk],   z2c);
      z2d = MFMA(a2_1, wfh[kk+1], z2d);
    }
  }
  floatx4 z1 = z1a + z1b;
  floatx4 z2 = (z2a + z2c) + (z2b + z2d);

  const bool l4 = (ln < 4);
  const bool evn = ((ln & 1) == 0);
  if (DOL1){
    #pragma unroll
    for (int r=0; r<4; ++r){
      const int row = rowbase + quad*4 + r;
      float z = z1[r] + xv[r]*wx + b1;
      float p4  = __shfl_xor(z, 4, 64);
      float p8  = __shfl_xor(z, 8, 64);
      float p12 = __shfl_xor(z, 12, 64);
      float ig = sigm(z), fg = sigm(p4), og = sigm(p8), gg = tanh_f(p12);
      float c = fg*c1v[r] + ig*gg;
      c1v[r] = c;
      float h = og*tanh_f(c);
      unsigned hu = (unsigned)__builtin_bit_cast(unsigned short, (_Float16)h);
      unsigned pn = (unsigned)__shfl_xor((int)hu, 1, 64);
      if (l4 && evn)
        st_f(rh1, o_h1w + (row*H + hcb + ln)*2,
             __builtin_bit_cast(float, hu | (pn<<16)));
    }
  }
  if (DOL2){
    floatx4 po4;
    #pragma unroll
    for (int r=0; r<4; ++r){
      const int row = rowbase + quad*4 + r;
      float z = z2[r] + b2;
      float p4  = __shfl_xor(z, 4, 64);
      float p8  = __shfl_xor(z, 8, 64);
      float p12 = __shfl_xor(z, 12, 64);
      float ig = sigm(z), fg = sigm(p4), og = sigm(p8), gg = tanh_f(p12);
      float c = fg*c2v[r] + ig*gg;
      c2v[r] = c;
      float h = og*tanh_f(c);
      unsigned hu = (unsigned)__builtin_bit_cast(unsigned short, (_Float16)h);
      unsigned pn = (unsigned)__shfl_xor((int)hu, 1, 64);
      if (l4 && evn)
        st_f(rh2, o_h2w + (row*H + hcb + ln)*2,
             __builtin_bit_cast(float, hu | (pn<<16)));
      float po = l4 ? h*wl : 0.f;
      po += __shfl_xor(po, 1, 64);
      po += __shfl_xor(po, 2, 64);
      po4[r] = po;                  // valid in ln==0 lanes
    }
    if (ln == 0){                   // 64B line per wave per t (rows 0..15)
      const int base = ((jwave*TP + t_out)*32)*4;
      st_f4(rop, base + quad*16, po4);
    }
  }
}

__global__ void reset_kernel(){
  if (threadIdx.x < 16*32)
    __hip_atomic_store(&g_flags[threadIdx.x], 0u, __ATOMIC_RELAXED,
                       __HIP_MEMORY_SCOPE_AGENT);
}

__global__ __launch_bounds__(BLOCK, 1) void sinernn_kernel(
    const float* __restrict__ seq, const float* __restrict__ Wx1,
    const float* __restrict__ bx1, const float* __restrict__ Wh1,
    const float* __restrict__ bh1, const float* __restrict__ Wx2,
    const float* __restrict__ bx2, const float* __restrict__ Wh2,
    const float* __restrict__ bh2, const float* __restrict__ Wl,
    const float* __restrict__ bl,  float* __restrict__ out)
{
  __shared__ __attribute__((aligned(16))) _Float16 lA1A[RPG*512];  // 16 KB
  __shared__ __attribute__((aligned(16))) _Float16 lA2A[RPG*512];  // 16 KB
  __shared__ __attribute__((aligned(16))) _Float16 lA1B[RPG*512];  // 16 KB
  __shared__ __attribute__((aligned(16))) _Float16 lA2B[RPG*512];  // 16 KB

  const int tid  = threadIdx.x;
  const int wg   = blockIdx.x;
  const int xcd  = wg & 7;
  const int slot = wg >> 3;            // 0..31
  const int ga   = xcd, gb = xcd + 8;  // this WG's two groups
  const int w    = tid >> 6;
  const int lane = tid & 63;
  const int ln   = lane & 15;
  const int quad = lane >> 4;
  const int rbA  = ga*RPG, rbB = gb*RPG;
  const int hcb  = slot*16 + w*4;      // this wave's 4 h-cols
  const int jA   = ga*128 + slot*4 + w;
  const int jB   = gb*128 + slot*4 + w;

  rsrc_t rh1 = mkrsrc((void*)&g_h1[0]);
  rsrc_t rh2 = mkrsrc((void*)&g_h2[0]);
  rsrc_t rop = mkrsrc((void*)&g_opart[0]);
  rsrc_t rsq = mkrsrc((void*)&g_seqT[0]);

  // gate-col: gate = ln>>2, h-col = hcb + (ln&3)
  const int gc = (ln>>2)*H + hcb + (ln&3);

  // ---- prologue: seqT transpose (16 t-values x 16 rows x 2 groups) ----
  for (int i = tid; i < 2*16*16; i += BLOCK){
    int g = i >> 8;
    int t = slot*16 + ((i>>4)&15), j = i & 15;
    int row = (g ? rbB : rbA) + j;
    st_f(rsq, (t*BATCH + row)*4, seq[row*T_SEQ + t]);
  }
  // zero h(-1) (buffer 1) for both groups' rows; redundant across slots
  for (int i = tid; i < RPG*H/2; i += BLOCK){
    st_f(rh1, HBYTES + rbA*H*2 + i*4, 0.f);
    st_f(rh2, HBYTES + rbA*H*2 + i*4, 0.f);
    st_f(rh1, HBYTES + rbB*H*2 + i*4, 0.f);
    st_f(rh2, HBYTES + rbB*H*2 + i*4, 0.f);
  }

  // ---- stage all three weight slices into VGPRs (192/lane, shared) ----
  half8 wf1[16], wfx[16], wfh[16];
  #pragma unroll
  for (int kk = 0; kk < 16; ++kk){
    #pragma unroll
    for (int j = 0; j < 8; ++j){
      const int k = kk*32 + quad*8 + j;
      wf1[kk][j] = (_Float16)Wh1[k*G4H + gc];
      wfx[kk][j] = (_Float16)Wx2[k*G4H + gc];
      wfh[kk][j] = (_Float16)Wh2[k*G4H + gc];
    }
  }
  const float b1 = bx1[gc] + bh1[gc];
  const float b2 = bx2[gc] + bh2[gc];
  const float wx = Wx1[gc];
  const float wl = (ln < 4) ? Wl[hcb + (ln&3)] : 0.f;
  const float blv = bl[0];

  float c1A[4] = {0.f,0.f,0.f,0.f}, c2A[4] = {0.f,0.f,0.f,0.f};
  float c1B[4] = {0.f,0.f,0.f,0.f}, c2B[4] = {0.f,0.f,0.f,0.f};

  bool alive = true;
  unsigned cur = 1;
  xsignal(ga, slot, 1, tid);           // prologue visible group-wide
  xsignal(gb, slot, 1, tid);

  // ---- main: round p = {phaseA(p), phaseB(p)}; phase computes h1(p),h2(p-1)
  for (int p = 0; p < T_SEQ; ++p){
    const int b_h1r = ((p+1)&1)*HBYTES;
    const int b_h1w = (p&1)*HBYTES;
    const int b_h2r = (p&1)*HBYTES;
    const int b_h2w = ((p+1)&1)*HBYTES;

    xwaitbar(ga, cur, alive, tid);
    if (p == 0)
      do_phase16<true,false,0>(rh1,rh2,rop,rsq, b_h1r,0, b_h1w,0,
                               0, 0, 0.f, -1, lA1A, lA2A, wf1,wfx,wfh,
                               b1,b2,wx,wl, c1A,c2A,
                               rbA, ga*128, jA, tid, ln, quad, hcb);
    else
      do_phase16<true,true,0>(rh1,rh2,rop,rsq, b_h1r,b_h2r, b_h1w,b_h2w,
                              p*BATCH*4, 0, 0.f, p-1, lA1A, lA2A, wf1,wfx,wfh,
                              b1,b2,wx,wl, c1A,c2A,
                              rbA, ga*128, jA, tid, ln, quad, hcb);
    xsignal(ga, slot, cur+1, tid);

    xwaitbar(gb, cur, alive, tid);
    if (p == 0)
      do_phase16<true,false,0>(rh1,rh2,rop,rsq, b_h1r,0, b_h1w,0,
                               0, 0, 0.f, -1, lA1B, lA2B, wf1,wfx,wfh,
                               b1,b2,wx,wl, c1B,c2B,
                               rbB, gb*128, jB, tid, ln, quad, hcb);
    else
      do_phase16<true,true,0>(rh1,rh2,rop,rsq, b_h1r,b_h2r, b_h1w,b_h2w,
                              p*BATCH*4, 0, 0.f, p-1, lA1B, lA2B, wf1,wfx,wfh,
                              b1,b2,wx,wl, c1B,c2B,
                              rbB, gb*128, jB, tid, ln, quad, hcb);
    xsignal(gb, slot, cur+1, tid);
    ++cur;
  }

  // ---- drain + autoregressive predict (one phase per group per round) ----
  for (int s = T_SEQ-1; s < TP; ++s){
    xwaitbar(ga, cur, alive, tid);
    do_phase16<false,true,0>(rh1,rh2,rop,rsq, (s&1)*HBYTES,((s+1)&1)*HBYTES,
                             0,(s&1)*HBYTES, 0, 0, 0.f, s,
                             lA1A, lA2A, wf1,wfx,wfh, b1,b2,wx,wl, c1A,c2A,
                             rbA, ga*128, jA, tid, ln, quad, hcb);
    xsignal(ga, slot, cur+1, tid);
    xwaitbar(gb, cur, alive, tid);
    do_phase16<false,true,0>(rh1,rh2,rop,rsq, (s&1)*HBYTES,((s+1)&1)*HBYTES,
                             0,(s&1)*HBYTES, 0, 0, 0.f, s,
                             lA1B, lA2B, wf1,wfx,wfh, b1,b2,wx,wl, c1B,c2B,
                             rbB, gb*128, jB, tid, ln, quad, hcb);
    xsignal(gb, slot, cur+1, tid);
    ++cur;

    if (s + 1 < TP){
      xwaitbar(ga, cur, alive, tid);
      do_phase16<true,false,1>(rh1,rh2,rop,rsq, (s&1)*HBYTES,0,
                               ((s+1)&1)*HBYTES,0, 0, s, blv, -1,
                               lA1A, lA2A, wf1,wfx,wfh, b1,b2,wx,wl, c1A,c2A,
                               rbA, ga*128, jA, tid, ln, quad, hcb);
      xsignal(ga, slot, cur+1, tid);
      xwaitbar(gb, cur, alive, tid);
      do_phase16<true,false,1>(rh1,rh2,rop,rsq, (s&1)*HBYTES,0,
                               ((s+1)&1)*HBYTES,0, 0, s, blv, -1,
                               lA1B, lA2B, wf1,wfx,wfh, b1,b2,wx,wl, c1B,c2B,
                               rbB, gb*128, jB, tid, ln, quad, hcb);
      xsignal(gb, slot, cur+1, tid);
      ++cur;
    }
  }
  xwaitbar(ga, cur, alive, tid);
  xwaitbar(gb, cur, alive, tid);

  // ---- epilogue: out[row][t] = sum over the group's 128 (slot',w') ----
  {
    float* lred = (float*)lA1A;          // reuse staging LDS
    const int row = tid & 15, part = tid >> 4;   // 16 parts x 8 j's
    for (int gsel = 0; gsel < 2; ++gsel){
      const int jb = (gsel ? gb : ga)*128;
      const int rb = (gsel ? rbB : rbA);
      for (int i = 0; i < 17; ++i){
        const int t = slot + i*32;
        float s = 0.f;
        #pragma unroll
        for (int q = 0; q < 8; ++q){
          const int j = jb + part*8 + q;
          s += ld_f(rop, ((j*TP + t)*32 + row)*4);
        }
        __syncthreads();
        lred[part*16 + row] = s;
        __syncthreads();
        if (tid < 16){
          float o = 0.f;
          #pragma unroll
          for (int p2 = 0; p2 < 16; ++p2) o += lred[p2*16 + tid];
          out[(rb + tid)*TP + t] = o + blv;
        }
      }
    }
  }
}

extern "C" void kernel_launch(void* const* d_in, const int* in_sizes, int n_in,
                              void* d_out, int out_size, void* d_ws, size_t ws_size,
                              hipStream_t stream) {
  const float* seq = (const float*)d_in[0];
  // d_in[1] = predict (=32, hardcoded)
  const float* Wx1 = (const float*)d_in[2];
  const float* bx1 = (const float*)d_in[3];
  const float* Wh1 = (const float*)d_in[4];
  const float* bh1 = (const float*)d_in[5];
  const float* Wx2 = (const float*)d_in[6];
  const float* bx2 = (const float*)d_in[7];
  const float* Wh2 = (const float*)d_in[8];
  const float* bh2 = (const float*)d_in[9];
  const float* Wl  = (const float*)d_in[10];
  const float* bl  = (const float*)d_in[11];
  float* out = (float*)d_out;

  reset_kernel<<<1, 512, 0, stream>>>();

  sinernn_kernel<<<dim3(GRID), dim3(BLOCK), 0, stream>>>(
      seq, Wx1, bx1, Wh1, bh1, Wx2, bx2, Wh2, bh2, Wl, bl, out);
}

// Round 15
// 4096.935 us; speedup vs baseline: 1.3277x; 1.0332x over previous
//
#include <hip/hip_runtime.h>

// ---------------- problem constants ----------------
#define T_SEQ 512
#define P_PRED 32
#define TP 544            // T_SEQ + P_PRED
#define BATCH 256
#define H 512
#define G4H 2048
// ---------------- kernel config --------------------
// FINAL = ROUND-11 (best verified, 4129us; 1.76x vs session start).
// Structure: 16 row-groups of 16 rows; group g on XCD g&7 (r4-validated
// placement). 256 WGs = 8 XCDs x 32 slots; WG (xcd,slot) serves groups
// xcd and xcd+8 per round: waitA,bodyA,sigA,waitB,bodyB,sigB — age-1
// flag pipelining hides barrier latency under the other group's body (r5,
// +20%). Slot s owns h-cols [16s,16s+16); wave w owns 4 h-cols (16 gate-
// cols); weights in VGPRs (192/lane; REQUIRES 1 wave/SIMD — r8 proved
// launch_bounds(...,2) spills them -> 24GB FETCH). Data traffic (h1,h2,
// opart,seqT) at SC0 = XCD-L2 coherent (r4, +9%); flags agent-scope LIC
// atomics ONLY (r6+r10: SC0-polled flags are unsound on this platform —
// two independent schemes both failed absmax). rcp-based activations in
// the parallel-redundant 4-per-lane form (r9 +20%; r13 proved the
// "deduplicated" form serializes the chain and is SLOWER). Staging gran
// c16+16*g4 = conflict-free LDS writes (r9: conflicts 3.7e8->1.5e8).
// MFMA accumulation split even/odd-kk: two 16-deep chains (r11, +3%;
// r14 proved 4-way split is null). Exhausted-lever ledger in session
// notes: remaining ~40% of phase time is drain + LIC flag RT + rendezvous
// skew — the serial recurrence's sync-latency floor for this protocol.
#define GRID 256
#define BLOCK 256
#define RPG 16              // rows per group
#define HBUF (BATCH*H)      // elements per h double-buffer slot
#define HBYTES (HBUF*2)
#define SCX 1               // CPol: SC0 -> bypass L1, coherent at XCD L2

typedef _Float16 half8 __attribute__((ext_vector_type(8)));
typedef float floatx4 __attribute__((ext_vector_type(4)));
typedef __amdgpu_buffer_rsrc_t rsrc_t;

#define MFMA(a,b,c) __builtin_amdgcn_mfma_f32_16x16x32_f16((a),(b),(c),0,0,0)

// ---------------- device-global state --------------
__device__ __attribute__((aligned(128))) _Float16 g_h1[2*HBUF];
__device__ __attribute__((aligned(128))) _Float16 g_h2[2*HBUF];
// o partials: [j = g*128 + slot*4 + w][t][32 slots (16 rows used)]
__device__ __attribute__((aligned(128))) float g_opart[(size_t)2048*TP*32];
__device__ __attribute__((aligned(128))) float g_seqT[T_SEQ*BATCH];  // [t][row]
__device__ __attribute__((aligned(128))) unsigned g_flags[16*32];    // 1 line/group

__device__ __forceinline__ rsrc_t mkrsrc(void* p){
  return __builtin_amdgcn_make_buffer_rsrc(p, (short)0, -1, 0x00020000);
}
__device__ __forceinline__ half8 ld_h8(rsrc_t r, int off){
  auto v = __builtin_amdgcn_raw_buffer_load_b128(r, off, 0, SCX);
  return __builtin_bit_cast(half8, v);
}
__device__ __forceinline__ floatx4 ld_f4(rsrc_t r, int off){
  auto v = __builtin_amdgcn_raw_buffer_load_b128(r, off, 0, SCX);
  return __builtin_bit_cast(floatx4, v);
}
__device__ __forceinline__ float ld_f(rsrc_t r, int off){
  auto v = __builtin_amdgcn_raw_buffer_load_b32(r, off, 0, SCX);
  return __builtin_bit_cast(float, v);
}
__device__ __forceinline__ void st_f(rsrc_t r, int off, float v){
  __builtin_amdgcn_raw_buffer_store_b32(__builtin_bit_cast(unsigned, v), r, off, 0, SCX);
}
__device__ __forceinline__ void st_f4(rsrc_t r, int off, floatx4 v){
  __builtin_amdgcn_raw_buffer_store_b128(v, r, off, 0, SCX);
}

// Fast activations: v_rcp_f32 (~1 ulp) instead of precise div (r9-proven).
__device__ __forceinline__ float sigm(float x){
  return __builtin_amdgcn_rcpf(1.0f + __expf(-x));
}
__device__ __forceinline__ float tanh_f(float x){
  return 1.0f - 2.0f*__builtin_amdgcn_rcpf(1.0f + __expf(2.0f*x));
}

// Release: drain stores (acked at own-XCD L2) + WG rendezvous, then wave-0
// lane-0 publishes the phase number at agent scope (LIC).
__device__ __forceinline__ void xsignal(int grp, int slot, unsigned target,
                                        int tid){
  __builtin_amdgcn_s_waitcnt(0);
  __syncthreads();
  if (tid == 0)
    __hip_atomic_store(&g_flags[grp*32 + slot], target, __ATOMIC_RELAXED,
                       __HIP_MEMORY_SCOPE_AGENT);
}

// Acquire: wave 0 polls the group's 32-slot flag line (lane&31), trailing
// __syncthreads releases the WG. Monotone phases, spin guard.
__device__ __forceinline__ void xwaitbar(int grp, unsigned target,
                                         bool& alive, int tid){
  if (tid < 64 && alive){
    int guard = 0;
    for (;;){
      unsigned f = __hip_atomic_load(&g_flags[grp*32 + (tid & 31)],
                                     __ATOMIC_RELAXED, __HIP_MEMORY_SCOPE_AGENT);
      if (__ballot(f >= target) == 0xFFFFFFFFFFFFFFFFull) break;
      __builtin_amdgcn_s_sleep(1);
      if (++guard > (1<<22)){ alive = false; break; }
    }
  }
  __syncthreads();
}

// One 16-row group phase. Stages group h slices L2->LDS (swizzled),
// MFMAs M=16 from LDS vs VGPR weights (split even/odd-kk chains).
// DOL1: h1=lstm(x,h1prev); XSEL 0 = x from seqT, 1 = x from o-partial
// gather (+bl). DOL2: h2=lstm(h1r,h2prev) + 64B opart store.
template<bool DOL1, bool DOL2, int XSEL>
__device__ __forceinline__ void do_phase16(
    rsrc_t rh1, rsrc_t rh2, rsrc_t rop, rsrc_t rsq,
    int o_h1r, int o_h2r, int o_h1w, int o_h2w,
    int o_x, int xs_t, float xadd, int t_out,
    _Float16* __restrict__ lA1, _Float16* __restrict__ lA2,
    const half8 (&wf1)[16], const half8 (&wfx)[16], const half8 (&wfh)[16],
    float b1, float b2, float wx, float wl,
    float (&c1v)[4], float (&c2v)[4],
    int rowbase, int jbase, int jwave, int tid, int ln, int quad, int hcb)
{
  // ---- stage A slices (16 rows x 512 fp16) from L2 into swizzled LDS ----
  // gran = c16 + 16*g4 (r9): row's 16 lanes span all 8 LDS bank-groups.
  {
    const int row = tid >> 4, c16 = tid & 15;
    const int gb1 = o_h1r + (rowbase + row)*H*2;
    const int gb2 = o_h2r + (rowbase + row)*H*2;
    #pragma unroll
    for (int g4 = 0; g4 < 4; ++g4){
      const int gran = c16 + 16*g4;
      const int loff = row*512 + ((gran ^ (row&7)) << 3);
      half8 v = ld_h8(rh1, gb1 + gran*16);
      *(half8*)(lA1 + loff) = v;
      if (DOL2){
        half8 u = ld_h8(rh2, gb2 + gran*16);
        *(half8*)(lA2 + loff) = u;
      }
    }
  }

  float xv[4];
  if (DOL1){
    if (XSEL == 0){
      floatx4 x4 = ld_f4(rsq, o_x + (rowbase + quad*4)*4);
      #pragma unroll
      for (int r=0; r<4; ++r) xv[r] = x4[r] + xadd;
    } else {
      #pragma unroll
      for (int r=0; r<4; ++r){
        const int lr = quad*4 + r;            // group-local row
        float s = 0.f;
        #pragma unroll
        for (int cc=0; cc<8; ++cc){
          const int j = jbase + ln*8 + cc;    // 128 owners of this group
          s += ld_f(rop, ((j*TP + xs_t)*32 + lr)*4);
        }
        s += __shfl_xor(s, 1, 64);
        s += __shfl_xor(s, 2, 64);
        s += __shfl_xor(s, 4, 64);
        s += __shfl_xor(s, 8, 64);
        xv[r] = s + xadd;
      }
    }
  }
  __syncthreads();   // staging visible WG-wide

  floatx4 zf4 = {0.f,0.f,0.f,0.f};
  floatx4 z1a = zf4, z1b = zf4, z2a = zf4, z2b = zf4;

  #pragma unroll
  for (int kk = 0; kk < 16; kk += 2){
    const int sw0 = (((kk*4 + quad) ^ (ln&7)) << 3);
    const int sw1 = ((((kk+1)*4 + quad) ^ (ln&7)) << 3);
    half8 a1_0 = *(const half8*)(lA1 + ln*512 + sw0);
    half8 a1_1 = *(const half8*)(lA1 + ln*512 + sw1);
    if (DOL1){
      z1a = MFMA(a1_0, wf1[kk],   z1a);
      z1b = MFMA(a1_1, wf1[kk+1], z1b);
    }
    if (DOL2){
      z2a = MFMA(a1_0, wfx[kk],   z2a);
      z2b = MFMA(a1_1, wfx[kk+1], z2b);
      half8 a2_0 = *(const half8*)(lA2 + ln*512 + sw0);
      half8 a2_1 = *(const half8*)(lA2 + ln*512 + sw1);
      z2a = MFMA(a2_0, wfh[kk],   z2a);
      z2b = MFMA(a2_1, wfh[kk+1], z2b);
    }
  }
  floatx4 z1 = z1a + z1b;
  floatx4 z2 = z2a + z2b;

  const bool l4 = (ln < 4);
  const bool evn = ((ln & 1) == 0);
  if (DOL1){
    #pragma unroll
    for (int r=0; r<4; ++r){
      const int row = rowbase + quad*4 + r;
      float z = z1[r] + xv[r]*wx + b1;
      float p4  = __shfl_xor(z, 4, 64);
      float p8  = __shfl_xor(z, 8, 64);
      float p12 = __shfl_xor(z, 12, 64);
      float ig = sigm(z), fg = sigm(p4), og = sigm(p8), gg = tanh_f(p12);
      float c = fg*c1v[r] + ig*gg;
      c1v[r] = c;
      float h = og*tanh_f(c);
      unsigned hu = (unsigned)__builtin_bit_cast(unsigned short, (_Float16)h);
      unsigned pn = (unsigned)__shfl_xor((int)hu, 1, 64);
      if (l4 && evn)
        st_f(rh1, o_h1w + (row*H + hcb + ln)*2,
             __builtin_bit_cast(float, hu | (pn<<16)));
    }
  }
  if (DOL2){
    floatx4 po4;
    #pragma unroll
    for (int r=0; r<4; ++r){
      const int row = rowbase + quad*4 + r;
      float z = z2[r] + b2;
      float p4  = __shfl_xor(z, 4, 64);
      float p8  = __shfl_xor(z, 8, 64);
      float p12 = __shfl_xor(z, 12, 64);
      float ig = sigm(z), fg = sigm(p4), og = sigm(p8), gg = tanh_f(p12);
      float c = fg*c2v[r] + ig*gg;
      c2v[r] = c;
      float h = og*tanh_f(c);
      unsigned hu = (unsigned)__builtin_bit_cast(unsigned short, (_Float16)h);
      unsigned pn = (unsigned)__shfl_xor((int)hu, 1, 64);
      if (l4 && evn)
        st_f(rh2, o_h2w + (row*H + hcb + ln)*2,
             __builtin_bit_cast(float, hu | (pn<<16)));
      float po = l4 ? h*wl : 0.f;
      po += __shfl_xor(po, 1, 64);
      po += __shfl_xor(po, 2, 64);
      po4[r] = po;                  // valid in ln==0 lanes
    }
    if (ln == 0){                   // 64B line per wave per t (rows 0..15)
      const int base = ((jwave*TP + t_out)*32)*4;
      st_f4(rop, base + quad*16, po4);
    }
  }
}

__global__ void reset_kernel(){
  if (threadIdx.x < 16*32)
    __hip_atomic_store(&g_flags[threadIdx.x], 0u, __ATOMIC_RELAXED,
                       __HIP_MEMORY_SCOPE_AGENT);
}

__global__ __launch_bounds__(BLOCK, 1) void sinernn_kernel(
    const float* __restrict__ seq, const float* __restrict__ Wx1,
    const float* __restrict__ bx1, const float* __restrict__ Wh1,
    const float* __restrict__ bh1, const float* __restrict__ Wx2,
    const float* __restrict__ bx2, const float* __restrict__ Wh2,
    const float* __restrict__ bh2, const float* __restrict__ Wl,
    const float* __restrict__ bl,  float* __restrict__ out)
{
  __shared__ __attribute__((aligned(16))) _Float16 lA1A[RPG*512];  // 16 KB
  __shared__ __attribute__((aligned(16))) _Float16 lA2A[RPG*512];  // 16 KB
  __shared__ __attribute__((aligned(16))) _Float16 lA1B[RPG*512];  // 16 KB
  __shared__ __attribute__((aligned(16))) _Float16 lA2B[RPG*512];  // 16 KB

  const int tid  = threadIdx.x;
  const int wg   = blockIdx.x;
  const int xcd  = wg & 7;
  const int slot = wg >> 3;            // 0..31
  const int ga   = xcd, gb = xcd + 8;  // this WG's two groups
  const int w    = tid >> 6;
  const int lane = tid & 63;
  const int ln   = lane & 15;
  const int quad = lane >> 4;
  const int rbA  = ga*RPG, rbB = gb*RPG;
  const int hcb  = slot*16 + w*4;      // this wave's 4 h-cols
  const int jA   = ga*128 + slot*4 + w;
  const int jB   = gb*128 + slot*4 + w;

  rsrc_t rh1 = mkrsrc((void*)&g_h1[0]);
  rsrc_t rh2 = mkrsrc((void*)&g_h2[0]);
  rsrc_t rop = mkrsrc((void*)&g_opart[0]);
  rsrc_t rsq = mkrsrc((void*)&g_seqT[0]);

  // gate-col: gate = ln>>2, h-col = hcb + (ln&3)
  const int gc = (ln>>2)*H + hcb + (ln&3);

  // ---- prologue: seqT transpose (16 t-values x 16 rows x 2 groups) ----
  for (int i = tid; i < 2*16*16; i += BLOCK){
    int g = i >> 8;
    int t = slot*16 + ((i>>4)&15), j = i & 15;
    int row = (g ? rbB : rbA) + j;
    st_f(rsq, (t*BATCH + row)*4, seq[row*T_SEQ + t]);
  }
  // zero h(-1) (buffer 1) for both groups' rows; redundant across slots
  for (int i = tid; i < RPG*H/2; i += BLOCK){
    st_f(rh1, HBYTES + rbA*H*2 + i*4, 0.f);
    st_f(rh2, HBYTES + rbA*H*2 + i*4, 0.f);
    st_f(rh1, HBYTES + rbB*H*2 + i*4, 0.f);
    st_f(rh2, HBYTES + rbB*H*2 + i*4, 0.f);
  }

  // ---- stage all three weight slices into VGPRs (192/lane, shared) ----
  half8 wf1[16], wfx[16], wfh[16];
  #pragma unroll
  for (int kk = 0; kk < 16; ++kk){
    #pragma unroll
    for (int j = 0; j < 8; ++j){
      const int k = kk*32 + quad*8 + j;
      wf1[kk][j] = (_Float16)Wh1[k*G4H + gc];
      wfx[kk][j] = (_Float16)Wx2[k*G4H + gc];
      wfh[kk][j] = (_Float16)Wh2[k*G4H + gc];
    }
  }
  const float b1 = bx1[gc] + bh1[gc];
  const float b2 = bx2[gc] + bh2[gc];
  const float wx = Wx1[gc];
  const float wl = (ln < 4) ? Wl[hcb + (ln&3)] : 0.f;
  const float blv = bl[0];

  float c1A[4] = {0.f,0.f,0.f,0.f}, c2A[4] = {0.f,0.f,0.f,0.f};
  float c1B[4] = {0.f,0.f,0.f,0.f}, c2B[4] = {0.f,0.f,0.f,0.f};

  bool alive = true;
  unsigned cur = 1;
  xsignal(ga, slot, 1, tid);           // prologue visible group-wide
  xsignal(gb, slot, 1, tid);

  // ---- main: round p = {phaseA(p), phaseB(p)}; phase computes h1(p),h2(p-1)
  for (int p = 0; p < T_SEQ; ++p){
    const int b_h1r = ((p+1)&1)*HBYTES;
    const int b_h1w = (p&1)*HBYTES;
    const int b_h2r = (p&1)*HBYTES;
    const int b_h2w = ((p+1)&1)*HBYTES;

    xwaitbar(ga, cur, alive, tid);
    if (p == 0)
      do_phase16<true,false,0>(rh1,rh2,rop,rsq, b_h1r,0, b_h1w,0,
                               0, 0, 0.f, -1, lA1A, lA2A, wf1,wfx,wfh,
                               b1,b2,wx,wl, c1A,c2A,
                               rbA, ga*128, jA, tid, ln, quad, hcb);
    else
      do_phase16<true,true,0>(rh1,rh2,rop,rsq, b_h1r,b_h2r, b_h1w,b_h2w,
                              p*BATCH*4, 0, 0.f, p-1, lA1A, lA2A, wf1,wfx,wfh,
                              b1,b2,wx,wl, c1A,c2A,
                              rbA, ga*128, jA, tid, ln, quad, hcb);
    xsignal(ga, slot, cur+1, tid);

    xwaitbar(gb, cur, alive, tid);
    if (p == 0)
      do_phase16<true,false,0>(rh1,rh2,rop,rsq, b_h1r,0, b_h1w,0,
                               0, 0, 0.f, -1, lA1B, lA2B, wf1,wfx,wfh,
                               b1,b2,wx,wl, c1B,c2B,
                               rbB, gb*128, jB, tid, ln, quad, hcb);
    else
      do_phase16<true,true,0>(rh1,rh2,rop,rsq, b_h1r,b_h2r, b_h1w,b_h2w,
                              p*BATCH*4, 0, 0.f, p-1, lA1B, lA2B, wf1,wfx,wfh,
                              b1,b2,wx,wl, c1B,c2B,
                              rbB, gb*128, jB, tid, ln, quad, hcb);
    xsignal(gb, slot, cur+1, tid);
    ++cur;
  }

  // ---- drain + autoregressive predict (one phase per group per round) ----
  for (int s = T_SEQ-1; s < TP; ++s){
    xwaitbar(ga, cur, alive, tid);
    do_phase16<false,true,0>(rh1,rh2,rop,rsq, (s&1)*HBYTES,((s+1)&1)*HBYTES,
                             0,(s&1)*HBYTES, 0, 0, 0.f, s,
                             lA1A, lA2A, wf1,wfx,wfh, b1,b2,wx,wl, c1A,c2A,
                             rbA, ga*128, jA, tid, ln, quad, hcb);
    xsignal(ga, slot, cur+1, tid);
    xwaitbar(gb, cur, alive, tid);
    do_phase16<false,true,0>(rh1,rh2,rop,rsq, (s&1)*HBYTES,((s+1)&1)*HBYTES,
                             0,(s&1)*HBYTES, 0, 0, 0.f, s,
                             lA1B, lA2B, wf1,wfx,wfh, b1,b2,wx,wl, c1B,c2B,
                             rbB, gb*128, jB, tid, ln, quad, hcb);
    xsignal(gb, slot, cur+1, tid);
    ++cur;

    if (s + 1 < TP){
      xwaitbar(ga, cur, alive, tid);
      do_phase16<true,false,1>(rh1,rh2,rop,rsq, (s&1)*HBYTES,0,
                               ((s+1)&1)*HBYTES,0, 0, s, blv, -1,
                               lA1A, lA2A, wf1,wfx,wfh, b1,b2,wx,wl, c1A,c2A,
                               rbA, ga*128, jA, tid, ln, quad, hcb);
      xsignal(ga, slot, cur+1, tid);
      xwaitbar(gb, cur, alive, tid);
      do_phase16<true,false,1>(rh1,rh2,rop,rsq, (s&1)*HBYTES,0,
                               ((s+1)&1)*HBYTES,0, 0, s, blv, -1,
                               lA1B, lA2B, wf1,wfx,wfh, b1,b2,wx,wl, c1B,c2B,
                               rbB, gb*128, jB, tid, ln, quad, hcb);
      xsignal(gb, slot, cur+1, tid);
      ++cur;
    }
  }
  xwaitbar(ga, cur, alive, tid);
  xwaitbar(gb, cur, alive, tid);

  // ---- epilogue: out[row][t] = sum over the group's 128 (slot',w') ----
  {
    float* lred = (float*)lA1A;          // reuse staging LDS
    const int row = tid & 15, part = tid >> 4;   // 16 parts x 8 j's
    for (int gsel = 0; gsel < 2; ++gsel){
      const int jb = (gsel ? gb : ga)*128;
      const int rb = (gsel ? rbB : rbA);
      for (int i = 0; i < 17; ++i){
        const int t = slot + i*32;
        float s = 0.f;
        #pragma unroll
        for (int q = 0; q < 8; ++q){
          const int j = jb + part*8 + q;
          s += ld_f(rop, ((j*TP + t)*32 + row)*4);
        }
        __syncthreads();
        lred[part*16 + row] = s;
        __syncthreads();
        if (tid < 16){
          float o = 0.f;
          #pragma unroll
          for (int p2 = 0; p2 < 16; ++p2) o += lred[p2*16 + tid];
          out[(rb + tid)*TP + t] = o + blv;
        }
      }
    }
  }
}

extern "C" void kernel_launch(void* const* d_in, const int* in_sizes, int n_in,
                              void* d_out, int out_size, void* d_ws, size_t ws_size,
                              hipStream_t stream) {
  const float* seq = (const float*)d_in[0];
  // d_in[1] = predict (=32, hardcoded)
  const float* Wx1 = (const float*)d_in[2];
  const float* bx1 = (const float*)d_in[3];
  const float* Wh1 = (const float*)d_in[4];
  const float* bh1 = (const float*)d_in[5];
  const float* Wx2 = (const float*)d_in[6];
  const float* bx2 = (const float*)d_in[7];
  const float* Wh2 = (const float*)d_in[8];
  const float* bh2 = (const float*)d_in[9];
  const float* Wl  = (const float*)d_in[10];
  const float* bl  = (const float*)d_in[11];
  float* out = (float*)d_out;

  reset_kernel<<<1, 512, 0, stream>>>();

  sinernn_kernel<<<dim3(GRID), dim3(BLOCK), 0, stream>>>(
      seq, Wx1, bx1, Wh1, bh1, Wx2, bx2, Wh2, bh2, Wl, bl, out);
}